// Round 7
// baseline (139.691 us; speedup 1.0000x reference)
//
#include <hip/hip_runtime.h>
#include <stdint.h>

// inputs [B=64, T=256, D=1024] f32; tanh -> sequential dual-threshold
// integrate-and-fire scan over T per (b,d). Serial over T (fp rounding of
// v depends on spike history -> no parallel scan). 65536 sequences.
//
// R7 = R6 structure (all-dwordx4 global traffic via LDS transpose tiles,
// raw s_barrier that never drains vmcnt) with the R6 spill bug fixed:
// CT 32->16 halves the live register set (R6: VGPR=88 allocated vs ~96
// live -> scratch spills -> +50MB HBM traffic -> 56us). Live set now:
// cur 4xfloat4 (16) + rr[16] (16) + temps ~35 => fits comfortably.
#define B_DIM 64
#define T_STEPS 256
#define D_DIM 1024
#define CT 16                   // timesteps per chunk
#define CHUNKS (T_STEPS / CT)   // 16
#define TPB 256
#define DSLICE 256              // d-columns per block

// XLA/Eigen f32 tanh rational approximation — bit-exact vs jnp.tanh
// (verified rounds 1-6: absmax = 0.0). DO NOT change the FMA structure.
__device__ __forceinline__ float xla_tanhf(float x) {
    const float kClamp = 7.90531110763549805f;
    float xc = fminf(fmaxf(x, -kClamp), kClamp);
    float x2 = xc * xc;
    float p = __builtin_fmaf(x2, -2.76076847742355e-16f, 2.00018790482477e-13f);
    p = __builtin_fmaf(x2, p, -8.60467152213735e-11f);
    p = __builtin_fmaf(x2, p, 5.12229709037114e-08f);
    p = __builtin_fmaf(x2, p, 1.48572235717979e-05f);
    p = __builtin_fmaf(x2, p, 6.37261928875436e-04f);
    p = __builtin_fmaf(x2, p, 4.89352455891786e-03f);
    p = xc * p;
    float q = __builtin_fmaf(x2, 1.19825839466702e-06f, 1.18534705686654e-04f);
    q = __builtin_fmaf(x2, q, 2.26843463243900e-03f);
    q = __builtin_fmaf(x2, q, 4.89352518554385e-03f);
    float r = p / q;           // IEEE divide — required for bit-exactness
    return (fabsf(x) < 0.0004f) ? x : r;
}

// Raw workgroup barrier: drains only this wave's LDS ops (lgkmcnt), NOT
// vmcnt — prefetched global loads stay in flight across it. This is the
// whole point vs __syncthreads (which drains vmcnt(0) and serialized R2/R5).
__device__ __forceinline__ void wg_barrier() {
    asm volatile("s_waitcnt lgkmcnt(0)\n\ts_barrier" ::: "memory");
}

__global__ __launch_bounds__(TPB, 1)
void spike_scan_kernel(const float* __restrict__ in, float* __restrict__ out) {
    __shared__ float lds_in[CT][DSLICE];    // 16 KB: chunk of raw inputs
    __shared__ float lds_out[CT][DSLICE];   // 16 KB: chunk of spike outputs

    const int tid = threadIdx.x;
    const int blk = blockIdx.x;          // 0..255 -> 1 block/CU
    const int b   = blk >> 2;
    const int d0  = (blk & 3) << 8;      // 256-wide d-slice (1KB rows)
    const size_t base = (size_t)b * (T_STEPS * D_DIM) + d0;
    const int w = tid >> 6;              // wave 0..3 owns rows 4w..4w+3
    const int l = tid & 63;

    const float* inb = in + base;
    float* outb = out + base;

    float4 cur[4];
    // prologue: load chunk 0 (4 x dwordx4 per wave = 4 KB/wave in flight)
    #pragma unroll
    for (int r = 0; r < 4; ++r)
        cur[r] = ((const float4*)(inb + (size_t)(4 * w + r) * D_DIM))[l];

    float v = 0.0f;

    #pragma unroll 1
    for (int c = 0; c < CHUNKS; ++c) {
        // stage chunk c -> LDS (ds_write_b128; compiler waits only on the
        // 4 specific loads feeding these writes)
        #pragma unroll
        for (int r = 0; r < 4; ++r)
            *(float4*)&lds_in[4 * w + r][4 * l] = cur[r];
        wg_barrier();                    // chunk c visible block-wide

        // prefetch chunk c+1; loads stay outstanding across the entire
        // scan + store phases (raw barriers never drain vmcnt)
        if (c + 1 < CHUNKS) {
            const float* inn = inb + (size_t)(c + 1) * CT * D_DIM;
            #pragma unroll
            for (int r = 0; r < 4; ++r)
                cur[r] = ((const float4*)(inn + (size_t)(4 * w + r) * D_DIM))[l];
        }
        __builtin_amdgcn_sched_barrier(0);   // pin load issue before the scan

        // scan: batch 16 LDS column reads + 16 tanh (max ILP), then the
        // serial v-chain; spikes land in the LDS out-tile (stride-4B
        // columns: 2 lanes/bank = conflict-free)
        float rr[CT];
        #pragma unroll
        for (int u = 0; u < CT; ++u) rr[u] = lds_in[u][tid];
        #pragma unroll
        for (int u = 0; u < CT; ++u) rr[u] = xla_tanhf(rr[u]);
        #pragma unroll
        for (int u = 0; u < CT; ++u) {
            v = __builtin_fmaf(rr[u], 0.01f, v);    // v += r*DT
            float sp = (v >= 1.0f)  ? 1.0f : 0.0f;
            float sn = (v <= -1.0f) ? 1.0f : 0.0f;
            v = (v - sp) + sn;                      // subtractive reset (exact)
            lds_out[u][tid] = (sp - sn) * 100.0f;   // ±100.0f exactly
        }
        wg_barrier();                    // out-tile complete block-wide

        // wide store: rows of the out-tile as dwordx4 (1 KB/wave-instr).
        // (Next iteration's lds_in/lds_out writes are safe: each wave's
        // row reads here drain via lgkmcnt before its next barrier.)
        float* outc = outb + (size_t)c * CT * D_DIM;
        #pragma unroll
        for (int r = 0; r < 4; ++r) {
            float4 o4 = *(const float4*)&lds_out[4 * w + r][4 * l];
            ((float4*)(outc + (size_t)(4 * w + r) * D_DIM))[l] = o4;
        }
    }
}

extern "C" void kernel_launch(void* const* d_in, const int* in_sizes, int n_in,
                              void* d_out, int out_size, void* d_ws, size_t ws_size,
                              hipStream_t stream) {
    const float* in = (const float*)d_in[0];
    float* out = (float*)d_out;
    dim3 block(TPB);
    dim3 grid(B_DIM * (D_DIM / DSLICE));  // 256 blocks -> 1 per CU
    spike_scan_kernel<<<grid, block, 0, stream>>>(in, out);
}

// Round 8
// 129.463 us; speedup vs baseline: 1.0790x; 1.0790x over previous
//
#include <hip/hip_runtime.h>
#include <stdint.h>

// inputs [B=64, T=256, D=1024] f32; tanh -> sequential dual-threshold
// integrate-and-fire scan over T per (b,d). Serial over T (fp rounding of
// v depends on spike history -> no parallel scan). 65536 sequences.
//
// R8: producer/consumer, all-wide vmem, single raw barrier per chunk.
//  - waves 0-3: memory only. float4 loads (distance-2, reg double-buffer,
//    statically unrolled phases -> no cross-iteration copies) -> ds_write_b128
//    raw-input tile; ds_read_b128 spike tile -> float4 stores.
//  - waves 4-7: compute only. Batched LDS column reads + tanh (ILP), serial
//    v-chain, spikes -> LDS out tile. Never touch global memory.
//  - raw s_barrier (lgkmcnt drain only, NEVER vmcnt) once per chunk: producer
//    loads stay in flight across phases (R2/R5 died on __syncthreads'
//    vmcnt(0) drain; R6/R7 died on 1-wave/SIMD LDS latency exposure).
// 8 waves/CU = 2/SIMD: producer vmem issue + consumer VALU co-scheduled.
#define B_DIM 64
#define T_STEPS 256
#define D_DIM 1024
#define CT 32                   // timesteps per chunk
#define PH (T_STEPS / CT)       // 8 phases
#define TPB 512
#define DSLICE 256              // d-columns per block

// XLA/Eigen f32 tanh rational approximation — bit-exact vs jnp.tanh
// (verified rounds 1-7: absmax = 0.0). DO NOT change the FMA structure.
__device__ __forceinline__ float xla_tanhf(float x) {
    const float kClamp = 7.90531110763549805f;
    float xc = fminf(fmaxf(x, -kClamp), kClamp);
    float x2 = xc * xc;
    float p = __builtin_fmaf(x2, -2.76076847742355e-16f, 2.00018790482477e-13f);
    p = __builtin_fmaf(x2, p, -8.60467152213735e-11f);
    p = __builtin_fmaf(x2, p, 5.12229709037114e-08f);
    p = __builtin_fmaf(x2, p, 1.48572235717979e-05f);
    p = __builtin_fmaf(x2, p, 6.37261928875436e-04f);
    p = __builtin_fmaf(x2, p, 4.89352455891786e-03f);
    p = xc * p;
    float q = __builtin_fmaf(x2, 1.19825839466702e-06f, 1.18534705686654e-04f);
    q = __builtin_fmaf(x2, q, 2.26843463243900e-03f);
    q = __builtin_fmaf(x2, q, 4.89352518554385e-03f);
    float r = p / q;           // IEEE divide — required for bit-exactness
    return (fabsf(x) < 0.0004f) ? x : r;
}

// Raw workgroup barrier: drains this wave's LDS ops only (lgkmcnt), NOT
// vmcnt — producer global loads/stores stay outstanding across it.
__device__ __forceinline__ void wg_barrier() {
    asm volatile("s_waitcnt lgkmcnt(0)\n\ts_barrier" ::: "memory");
}

__global__ __launch_bounds__(TPB, 1)
void spike_scan_kernel(const float* __restrict__ in, float* __restrict__ out) {
    __shared__ float rin[2][CT][DSLICE];    // 2 x 32 KB raw inputs
    __shared__ float rout[2][CT][DSLICE];   // 2 x 32 KB spike outputs (128 KB total)

    const int tid = threadIdx.x;
    const int blk = blockIdx.x;          // 0..255 -> 1 block/CU
    const int b   = blk >> 2;
    const int d0  = (blk & 3) << 8;      // 256-wide d-slice (1 KB rows)
    const size_t base = (size_t)b * (T_STEPS * D_DIM) + d0;
    const float* inb = in + base;
    float* outb = out + base;

    if (tid < 256) {
        // ================= producers: waves 0-3, memory only =============
        const int w = tid >> 6;          // wave owns rows 8w..8w+7 of a chunk
        const int l = tid & 63;

        float4 A[8], Bb[8];
        // gload(c,r): one dwordx4 per lane; a wave covers the full 1 KB row
        #define GLOAD(c, r) (((const float4*)(inb + ((size_t)(c) * CT + 8 * w + (r)) * D_DIM))[l])

        // prologue: chunk0 -> rin[0]; chunk1 -> A
        #pragma unroll
        for (int r = 0; r < 8; ++r) A[r] = GLOAD(0, r);
        #pragma unroll
        for (int r = 0; r < 8; ++r) *(float4*)&rin[0][8 * w + r][4 * l] = A[r];
        #pragma unroll
        for (int r = 0; r < 8; ++r) A[r] = GLOAD(1, r);
        wg_barrier();                    // phase "-1" end: rin[0] visible

        // phase c: issue loads(c+2); stage chunk c+1 (Areg, loaded a full
        // phase ago -> vmcnt wait is free); drain spikes(c-1) wide.
        #define PROD_PHASE(c, Areg, Breg) do {                                     \
            if ((c) + 2 < PH) {                                                    \
                _Pragma("unroll")                                                  \
                for (int r = 0; r < 8; ++r) Breg[r] = GLOAD((c) + 2, r);           \
            }                                                                      \
            if ((c) + 1 < PH) {                                                    \
                _Pragma("unroll")                                                  \
                for (int r = 0; r < 8; ++r)                                        \
                    *(float4*)&rin[((c) + 1) & 1][8 * w + r][4 * l] = Areg[r];     \
            }                                                                      \
            if ((c) >= 1) {                                                        \
                float4 o[8];                                                       \
                _Pragma("unroll")                                                  \
                for (int r = 0; r < 8; ++r)                                        \
                    o[r] = *(const float4*)&rout[((c) - 1) & 1][8 * w + r][4 * l]; \
                float* outc = outb + (size_t)((c) - 1) * CT * D_DIM;               \
                _Pragma("unroll")                                                  \
                for (int r = 0; r < 8; ++r)                                        \
                    ((float4*)(outc + (size_t)(8 * w + r) * D_DIM))[l] = o[r];     \
            }                                                                      \
            wg_barrier();                                                          \
        } while (0)

        PROD_PHASE(0, A, Bb);
        PROD_PHASE(1, Bb, A);
        PROD_PHASE(2, A, Bb);
        PROD_PHASE(3, Bb, A);
        PROD_PHASE(4, A, Bb);
        PROD_PHASE(5, Bb, A);
        PROD_PHASE(6, A, Bb);
        PROD_PHASE(7, Bb, A);

        // epilogue: spikes of chunk 7 (rout[7&1]=rout[1], complete after
        // the final barrier)
        {
            float4 o[8];
            #pragma unroll
            for (int r = 0; r < 8; ++r)
                o[r] = *(const float4*)&rout[1][8 * w + r][4 * l];
            float* outc = outb + (size_t)(PH - 1) * CT * D_DIM;
            #pragma unroll
            for (int r = 0; r < 8; ++r)
                ((float4*)(outc + (size_t)(8 * w + r) * D_DIM))[l] = o[r];
        }
    } else {
        // ================= consumers: waves 4-7, compute only ============
        const int ctid = tid - 256;      // d-column 0..255
        float v = 0.0f;
        wg_barrier();                    // matches producer prologue barrier

        #pragma unroll 1
        for (int c = 0; c < PH; ++c) {
            const int p = c & 1;
            float rr[CT];
            // batched column reads (stride 4B: 2 lanes/bank = conflict-free)
            #pragma unroll
            for (int u = 0; u < CT; ++u) rr[u] = rin[p][u][ctid];
            #pragma unroll
            for (int u = 0; u < CT; ++u) rr[u] = xla_tanhf(rr[u]);
            #pragma unroll
            for (int u = 0; u < CT; ++u) {
                v = __builtin_fmaf(rr[u], 0.01f, v);    // v += r*DT
                float sp = (v >= 1.0f)  ? 1.0f : 0.0f;
                float sn = (v <= -1.0f) ? 1.0f : 0.0f;
                v = (v - sp) + sn;                      // subtractive reset (exact)
                rout[p][u][ctid] = (sp - sn) * 100.0f;  // ±100.0f exactly
            }
            wg_barrier();                // phase c end
        }
    }
}

extern "C" void kernel_launch(void* const* d_in, const int* in_sizes, int n_in,
                              void* d_out, int out_size, void* d_ws, size_t ws_size,
                              hipStream_t stream) {
    const float* in = (const float*)d_in[0];
    float* out = (float*)d_out;
    dim3 block(TPB);
    dim3 grid(B_DIM * (D_DIM / DSLICE));  // 256 blocks -> 1 per CU
    spike_scan_kernel<<<grid, block, 0, stream>>>(in, out);
}